// Round 3
// baseline (209.183 us; speedup 1.0000x reference)
//
#include <hip/hip_runtime.h>
#include <hip/hip_bf16.h>
#include <cstdint>

#define HW 128
#define MASK_ELEMS (HW * HW)

typedef unsigned short ushort_t;
typedef __attribute__((ext_vector_type(4))) unsigned short ushort4_t;
typedef __attribute__((ext_vector_type(8))) short short8;
typedef __attribute__((ext_vector_type(4))) float f32x4;

__device__ __forceinline__ float bfu(ushort_t u) {
    union { unsigned int i; float f; } c;
    c.i = ((unsigned int)u) << 16;
    return c.f;
}
__device__ __forceinline__ float asf(unsigned int u) {
    union { unsigned int i; float f; } c;
    c.i = u;
    return c.f;
}
__device__ __forceinline__ ushort_t f2bf(float f) {
    union { float f; unsigned int i; } c;
    c.f = f;
    unsigned int r = c.i + 0x7FFFu + ((c.i >> 16) & 1u);  // RNE
    return (ushort_t)(r >> 16);
}

// ---------- kernel 1: per-point bilinear setup -> base idx + 4 packed bf16 weight products ----
// Taps are always lm[b], lm[b+1], lm[b+128], lm[b+129], all within [0,16384).
__global__ void kprep(const float* __restrict__ coords, int* __restrict__ idx,
                      uint2* __restrict__ wpk, int P) {
    int i = blockIdx.x * 256 + threadIdx.x;
    if (i >= P) return;
    float cx = coords[2 * i], cy = coords[2 * i + 1];
    float x = cx * (float)HW - 0.5f;
    float y = cy * (float)HW - 0.5f;
    float x0f = floorf(x), y0f = floorf(y);
    float wx1 = x - x0f, wy1 = y - y0f;
    float wx0 = 1.f - wx1, wy0 = 1.f - wy1;
    int x0 = (int)x0f, y0 = (int)y0f;

    float wxA = (x0 >= 0) ? wx0 : wx1;
    float wxB = (x0 >= 0 && x0 < HW - 1) ? wx1 : 0.f;
    float wyA = (y0 >= 0) ? wy0 : wy1;
    float wyB = (y0 >= 0 && y0 < HW - 1) ? wy1 : 0.f;
    int bx = max(x0, 0), by = max(y0, 0);
    if (bx > HW - 2) { bx = HW - 2; wxB = wxA; wxA = 0.f; }
    if (by > HW - 2) { by = HW - 2; wyB = wyA; wyA = 0.f; }

    idx[i] = by * HW + bx;
    wpk[i] = make_uint2((unsigned)f2bf(wxA * wyA) | ((unsigned)f2bf(wxB * wyA) << 16),
                        (unsigned)f2bf(wxA * wyB) | ((unsigned)f2bf(wxB * wyB) << 16));
}

template <int DO_SIG>
__device__ __forceinline__ float tap4(const ushort_t* lm, int b, unsigned wA, unsigned wB) {
    float w00 = asf(wA << 16), w01 = asf(wA & 0xffff0000u);
    float w10 = asf(wB << 16), w11 = asf(wB & 0xffff0000u);
    float v = w00 * bfu(lm[b]) + w01 * bfu(lm[b + 1])
            + w10 * bfu(lm[b + HW]) + w11 * bfu(lm[b + HW + 1]);
    if (DO_SIG) v = __builtin_amdgcn_rcpf(1.f + __expf(-v));
    return v;
}

// ---------- kernel 2: sample masks (bf16 LDS tile) -> bf16 samples + row sums ----------
template <int DO_SIG>
__global__ __launch_bounds__(256) void ksample(const float* __restrict__ masks,
                                               const int* __restrict__ idx,
                                               const uint2* __restrict__ wpk,
                                               ushort_t* __restrict__ samp,
                                               float* __restrict__ sum_out,
                                               const int* __restrict__ lvl, int P, int R) {
    if (*lvl >= 2) return;
    __shared__ ushort_t lm[MASK_ELEMS];  // 32 KB -> 5 blocks/CU
    int r = blockIdx.x, tid = threadIdx.x;
    const float* m = masks + (size_t)r * MASK_ELEMS;
    #pragma unroll
    for (int j = 0; j < MASK_ELEMS / 1024; ++j) {
        int o = j * 1024 + tid * 4;
        float4 v = *(const float4*)&m[o];
        ushort4_t p = {f2bf(v.x), f2bf(v.y), f2bf(v.z), f2bf(v.w)};
        *(ushort4_t*)&lm[o] = p;
    }
    __syncthreads();

    int nq = P >> 2;                      // point-quads (P % 4 == 0)
    int qchunk = nq / gridDim.y;
    int qb = blockIdx.y * qchunk;
    int qe = (blockIdx.y == gridDim.y - 1) ? nq : qb + qchunk;
    const int4* idx4 = (const int4*)idx;
    const uint4* w4 = (const uint4*)wpk;
    ushort4_t* s4 = (ushort4_t*)(samp + (size_t)r * P);

    float sum = 0.f;
    for (int q = qb + tid; q < qe; q += 256) {
        int4 id = idx4[q];
        uint4 wa = w4[2 * q], wb = w4[2 * q + 1];
        float v0 = tap4<DO_SIG>(lm, id.x, wa.x, wa.y);
        float v1 = tap4<DO_SIG>(lm, id.y, wa.z, wa.w);
        float v2 = tap4<DO_SIG>(lm, id.z, wb.x, wb.y);
        float v3 = tap4<DO_SIG>(lm, id.w, wb.z, wb.w);
        ushort4_t o = {f2bf(v0), f2bf(v1), f2bf(v2), f2bf(v3)};
        s4[q] = o;
        sum += (v0 + v1) + (v2 + v3);
    }

    __syncthreads();
    float* red = (float*)lm;
    red[tid] = sum;
    __syncthreads();
    for (int s2 = 128; s2 > 0; s2 >>= 1) {
        if (tid < s2) red[tid] += red[tid + s2];
        __syncthreads();
    }
    if (tid == 0) sum_out[blockIdx.y * R + r] = red[0];
}

// ---------- kernel 3: MFMA split-K GEMM: Cpart[ks][n][t] = sum_k S[n,k]*Tm[t,k] ----------
#define LDF(Aarr, Barr, kof)                                                              \
    do {                                                                                  \
        _Pragma("unroll") for (int m_ = 0; m_ < 3; ++m_)                                  \
            Aarr[m_] = *(const short8*)(pa + (size_t)m_ * 16 * P + (kof));                \
        _Pragma("unroll") for (int j_ = 0; j_ < 5; ++j_)                                  \
            Barr[j_] = *(const short8*)(pb + (size_t)j_ * 16 * P + (kof));                \
    } while (0)

#define FMAS(Aarr, Barr)                                                                  \
    do {                                                                                  \
        _Pragma("unroll") for (int m_ = 0; m_ < 3; ++m_) {                                \
            _Pragma("unroll") for (int j_ = 0; j_ < 5; ++j_)                              \
                acc[m_][j_] = __builtin_amdgcn_mfma_f32_16x16x32_bf16(                    \
                    Aarr[m_], Barr[j_], acc[m_][j_], 0, 0, 0);                            \
        }                                                                                 \
    } while (0)

__global__ __launch_bounds__(256) void kgemm(const ushort_t* __restrict__ S,
                                             const ushort_t* __restrict__ Tm,
                                             float* __restrict__ Cpart,
                                             const int* __restrict__ lvl,
                                             int N, int T, int P, int nsteps) {
    if (*lvl >= 2) return;
    int tid = threadIdx.x;
    int wid = tid >> 6, lane = tid & 63;
    int wm = wid >> 1, wt = wid & 1;
    int r = lane & 15, g = lane >> 4;
    int n0 = blockIdx.x * 96 + wm * 48;
    int t0 = wt * 80;
    size_t k0 = (size_t)blockIdx.y * nsteps * 32 + g * 8;
    const ushort_t* pa = S + (size_t)(n0 + r) * P + k0;
    const ushort_t* pb = Tm + (size_t)(t0 + r) * P + k0;

    f32x4 acc[3][5];
    #pragma unroll
    for (int m2 = 0; m2 < 3; ++m2)
        #pragma unroll
        for (int j2 = 0; j2 < 5; ++j2) acc[m2][j2] = (f32x4){0.f, 0.f, 0.f, 0.f};

    short8 a0[3], b0[5], a1[3], b1[5];
    LDF(a0, b0, 0);
    int ks = 0;
    for (; ks + 2 < nsteps; ks += 2) {
        LDF(a1, b1, (ks + 1) * 32);
        FMAS(a0, b0);
        LDF(a0, b0, (ks + 2) * 32);
        FMAS(a1, b1);
    }
    LDF(a1, b1, (ks + 1) * 32);
    FMAS(a0, b0);
    FMAS(a1, b1);

    size_t cb = (size_t)blockIdx.y * N * T;
    #pragma unroll
    for (int m2 = 0; m2 < 3; ++m2)
        #pragma unroll
        for (int j2 = 0; j2 < 5; ++j2)
            #pragma unroll
            for (int q = 0; q < 4; ++q) {
                int row = n0 + m2 * 16 + g * 4 + q;
                int col = t0 + j2 * 16 + r;
                Cpart[cb + (size_t)row * T + col] = acc[m2][j2][q];
            }
}

// ---------- kernel 4: epilogue ----------
__global__ void kfinal(const float* __restrict__ logits, const float* __restrict__ opts,
                       const float* __restrict__ tpts, const float* __restrict__ Cpart,
                       const float* __restrict__ ssum, const float* __restrict__ tsum4,
                       const int* __restrict__ lvl, float* __restrict__ out,
                       int N, int T, int nks) {
    int idx = blockIdx.x * 256 + threadIdx.x;
    if (idx >= N * T) return;
    int n = idx / T, t = idx - n * T;

    float lg = logits[n];
    float p = 1.f / (1.f + __expf(-lg));
    float pos = 0.25f * (1.f - p) * (1.f - p) * (-logf(p + 1e-8f));
    float neg = 0.75f * p * p * (-logf(1.f - p + 1e-8f));
    float ccls = pos - neg;

    float kp = 0.f;
    const float4* a4 = (const float4*)(opts + (size_t)n * 32);
    const float4* b4 = (const float4*)(tpts + (size_t)t * 32);
    #pragma unroll
    for (int j = 0; j < 8; ++j) {
        float4 a = a4[j], b = b4[j];
        kp += fabsf(a.x - b.x) + fabsf(a.y - b.y) + fabsf(a.z - b.z) + fabsf(a.w - b.w);
    }

    float dice = 0.f;
    if (*lvl < 2) {
        float dot = 0.f;
        for (int ks = 0; ks < nks; ++ks) dot += Cpart[(size_t)ks * N * T + idx];
        float ts = 0.f;
        #pragma unroll
        for (int ps = 0; ps < 4; ++ps) ts += tsum4[ps * T + t];
        dice = 1.f - (2.f * dot + 1.f) / (ssum[n] + ts + 1.f);
    }
    out[idx] = 2.f * ccls + 5.f * kp + 5.f * dice;
}

extern "C" void kernel_launch(void* const* d_in, const int* in_sizes, int n_in,
                              void* d_out, int out_size, void* d_ws, size_t ws_size,
                              hipStream_t stream) {
    const float* logits = (const float*)d_in[0];
    const float* cpts   = (const float*)d_in[1];
    const float* pmask  = (const float*)d_in[2];
    const float* tpts   = (const float*)d_in[3];
    const float* tmasks = (const float*)d_in[4];
    const float* coords = (const float*)d_in[5];
    const int*   lvl    = (const int*)d_in[6];
    float* out = (float*)d_out;

    int N = in_sizes[0];        // 2400
    int T = in_sizes[3] / 32;   // 160
    int P = in_sizes[5] / 2;    // 12544

    char* w = (char*)d_ws;
    auto alloc = [&](size_t bytes) {
        char* r = w;
        w += (bytes + 255) & ~(size_t)255;
        return r;
    };
    int*      idxb  = (int*)alloc((size_t)P * 4);
    uint2*    wpkb  = (uint2*)alloc((size_t)P * 8);
    ushort_t* tsamp = (ushort_t*)alloc((size_t)T * P * 2);
    ushort_t* S     = (ushort_t*)alloc((size_t)N * P * 2);
    float*    ssumb = (float*)alloc((size_t)N * 4);
    float*    tsum4 = (float*)alloc((size_t)4 * T * 4);
    size_t base_bytes = (size_t)(w - (char*)d_ws);

    int nks = 28;
    if (base_bytes + (size_t)nks * N * T * 4 > ws_size) nks = 14;
    if (base_bytes + (size_t)nks * N * T * 4 > ws_size) nks = 7;
    int nsteps = (P / 32) / nks;
    float* Cpart = (float*)alloc((size_t)nks * N * T * 4);

    kprep<<<(P + 255) / 256, 256, 0, stream>>>(coords, idxb, wpkb, P);
    ksample<0><<<dim3(T, 4), 256, 0, stream>>>(tmasks, idxb, wpkb, tsamp, tsum4, lvl, P, T);
    ksample<1><<<dim3(N, 1), 256, 0, stream>>>(pmask, idxb, wpkb, S, ssumb, lvl, P, N);
    kgemm<<<dim3(N / 96, nks), 256, 0, stream>>>(S, tsamp, Cpart, lvl, N, T, P, nsteps);
    kfinal<<<(N * T + 255) / 256, 256, 0, stream>>>(logits, cpts, tpts, Cpart, ssumb, tsum4,
                                                    lvl, out, N, T, nks);
}

// Round 4
// 145.975 us; speedup vs baseline: 1.4330x; 1.4330x over previous
//
#include <hip/hip_runtime.h>
#include <hip/hip_bf16.h>
#include <cstdint>

#define HW 128
#define MASK_ELEMS (HW * HW)

typedef unsigned short ushort_t;
typedef __attribute__((ext_vector_type(4))) unsigned short ushort4_t;
typedef __attribute__((ext_vector_type(8))) short short8;
typedef __attribute__((ext_vector_type(4))) float f32x4;

__device__ __forceinline__ float asf(unsigned int u) {
    union { unsigned int i; float f; } c;
    c.i = u;
    return c.f;
}
__device__ __forceinline__ ushort_t f2bf(float f) {
    union { float f; unsigned int i; } c;
    c.f = f;
    unsigned int r = c.i + 0x7FFFu + ((c.i >> 16) & 1u);  // RNE
    return (ushort_t)(r >> 16);
}

// ---------- kernel 1: per-point bilinear setup -> base idx + 4 packed bf16 weight products ----
// Base b is clamped so bx<=126, by<=126: taps {b, b+1, b+128, b+129} all in-tile, and the
// packed-pair LDS tile (see ksample) is only ever indexed at x<=126.
__global__ void kprep(const float* __restrict__ coords, int* __restrict__ idx,
                      uint2* __restrict__ wpk, int P) {
    int i = blockIdx.x * 256 + threadIdx.x;
    if (i >= P) return;
    float cx = coords[2 * i], cy = coords[2 * i + 1];
    float x = cx * (float)HW - 0.5f;
    float y = cy * (float)HW - 0.5f;
    float x0f = floorf(x), y0f = floorf(y);
    float wx1 = x - x0f, wy1 = y - y0f;
    float wx0 = 1.f - wx1, wy0 = 1.f - wy1;
    int x0 = (int)x0f, y0 = (int)y0f;

    float wxA = (x0 >= 0) ? wx0 : wx1;
    float wxB = (x0 >= 0 && x0 < HW - 1) ? wx1 : 0.f;
    float wyA = (y0 >= 0) ? wy0 : wy1;
    float wyB = (y0 >= 0 && y0 < HW - 1) ? wy1 : 0.f;
    int bx = max(x0, 0), by = max(y0, 0);
    if (bx > HW - 2) { bx = HW - 2; wxB = wxA; wxA = 0.f; }
    if (by > HW - 2) { by = HW - 2; wyB = wyA; wyA = 0.f; }

    idx[i] = by * HW + bx;
    wpk[i] = make_uint2((unsigned)f2bf(wxA * wyA) | ((unsigned)f2bf(wxB * wyA) << 16),
                        (unsigned)f2bf(wxA * wyB) | ((unsigned)f2bf(wxB * wyB) << 16));
}

// One bilinear point from the packed-pair tile: 2 adjacent-base LDS words (-> ds_read2_b32).
template <int DO_SIG>
__device__ __forceinline__ float tap1(const unsigned* lmp, int b, unsigned wA, unsigned wB) {
    unsigned r0 = lmp[b];        // (m[b], m[b+1])
    unsigned r1 = lmp[b + HW];   // (m[b+128], m[b+129])
    float v = asf(wA << 16) * asf(r0 << 16) + asf(wA & 0xffff0000u) * asf(r0 & 0xffff0000u)
            + asf(wB << 16) * asf(r1 << 16) + asf(wB & 0xffff0000u) * asf(r1 & 0xffff0000u);
    if (DO_SIG) v = __builtin_amdgcn_rcpf(1.f + __expf(-v));
    return v;
}

// ---------- kernel 2: sample masks (packed-pair bf16 LDS) -> bf16 samples + row sums ----------
template <int DO_SIG>
__global__ __launch_bounds__(256) void ksample(const float* __restrict__ masks,
                                               const int* __restrict__ idx,
                                               const uint2* __restrict__ wpk,
                                               ushort_t* __restrict__ samp,
                                               float* __restrict__ sum_out,
                                               const int* __restrict__ lvl, int P, int R) {
    if (*lvl >= 2) return;
    __shared__ unsigned int lmp[MASK_ELEMS];  // 64 KB: lmp[i] = (bf16 m[i], bf16 m[i+1])
    int r = blockIdx.x, tid = threadIdx.x;
    const float* m = masks + (size_t)r * MASK_ELEMS;
    #pragma unroll
    for (int j = 0; j < MASK_ELEMS / 1024; ++j) {
        int o = j * 1024 + tid * 4;
        float4 v = *(const float4*)&m[o];
        float nx = m[min(o + 4, MASK_ELEMS - 1)];
        unsigned e0 = (unsigned)f2bf(v.x) | ((unsigned)f2bf(v.y) << 16);
        unsigned e1 = (unsigned)f2bf(v.y) | ((unsigned)f2bf(v.z) << 16);
        unsigned e2 = (unsigned)f2bf(v.z) | ((unsigned)f2bf(v.w) << 16);
        unsigned e3 = (unsigned)f2bf(v.w) | ((unsigned)f2bf(nx) << 16);
        *(uint4*)&lmp[o] = make_uint4(e0, e1, e2, e3);
    }
    __syncthreads();

    int nq = P >> 2;                      // point-quads (P % 4 == 0)
    int qchunk = nq / gridDim.y;
    int qb = blockIdx.y * qchunk;
    int qe = (blockIdx.y == gridDim.y - 1) ? nq : qb + qchunk;
    const int4* idx4 = (const int4*)idx;
    const uint4* w4 = (const uint4*)wpk;
    ushort4_t* s4 = (ushort4_t*)(samp + (size_t)r * P);

    float sum = 0.f;
    int q = qb + tid;
    if (q < qe) {
        int4 id = idx4[q];
        uint4 wa = w4[2 * q], wb = w4[2 * q + 1];
        while (q < qe) {
            int qn = q + 256;
            int4 idn;
            uint4 wan, wbn;
            if (qn < qe) {                // prefetch next iteration's metadata (L2-latency hide)
                idn = idx4[qn];
                wan = w4[2 * qn];
                wbn = w4[2 * qn + 1];
            }
            float v0 = tap1<DO_SIG>(lmp, id.x, wa.x, wa.y);
            float v1 = tap1<DO_SIG>(lmp, id.y, wa.z, wa.w);
            float v2 = tap1<DO_SIG>(lmp, id.z, wb.x, wb.y);
            float v3 = tap1<DO_SIG>(lmp, id.w, wb.z, wb.w);
            ushort4_t o = {f2bf(v0), f2bf(v1), f2bf(v2), f2bf(v3)};
            s4[q] = o;
            sum += (v0 + v1) + (v2 + v3);
            q = qn;
            id = idn; wa = wan; wb = wbn;
        }
    }

    __syncthreads();
    float* red = (float*)lmp;
    red[tid] = sum;
    __syncthreads();
    for (int s2 = 128; s2 > 0; s2 >>= 1) {
        if (tid < s2) red[tid] += red[tid + s2];
        __syncthreads();
    }
    if (tid == 0) sum_out[blockIdx.y * R + r] = red[0];
}

// ---------- kernel 3: MFMA split-K GEMM: Cpart[ks][n][t] = sum_k S[n,k]*Tm[t,k] ----------
#define LDF(Aarr, Barr, kof)                                                              \
    do {                                                                                  \
        _Pragma("unroll") for (int m_ = 0; m_ < 3; ++m_)                                  \
            Aarr[m_] = *(const short8*)(pa + (size_t)m_ * 16 * P + (kof));                \
        _Pragma("unroll") for (int j_ = 0; j_ < 5; ++j_)                                  \
            Barr[j_] = *(const short8*)(pb + (size_t)j_ * 16 * P + (kof));                \
    } while (0)

#define FMAS(Aarr, Barr)                                                                  \
    do {                                                                                  \
        _Pragma("unroll") for (int m_ = 0; m_ < 3; ++m_) {                                \
            _Pragma("unroll") for (int j_ = 0; j_ < 5; ++j_)                              \
                acc[m_][j_] = __builtin_amdgcn_mfma_f32_16x16x32_bf16(                    \
                    Aarr[m_], Barr[j_], acc[m_][j_], 0, 0, 0);                            \
        }                                                                                 \
    } while (0)

__global__ __launch_bounds__(256) void kgemm(const ushort_t* __restrict__ S,
                                             const ushort_t* __restrict__ Tm,
                                             float* __restrict__ Cpart,
                                             const int* __restrict__ lvl,
                                             int N, int T, int P, int nsteps) {
    if (*lvl >= 2) return;
    int tid = threadIdx.x;
    int wid = tid >> 6, lane = tid & 63;
    int wm = wid >> 1, wt = wid & 1;
    int r = lane & 15, g = lane >> 4;
    int n0 = blockIdx.x * 96 + wm * 48;
    int t0 = wt * 80;
    size_t k0 = (size_t)blockIdx.y * nsteps * 32 + g * 8;
    const ushort_t* pa = S + (size_t)(n0 + r) * P + k0;
    const ushort_t* pb = Tm + (size_t)(t0 + r) * P + k0;

    f32x4 acc[3][5];
    #pragma unroll
    for (int m2 = 0; m2 < 3; ++m2)
        #pragma unroll
        for (int j2 = 0; j2 < 5; ++j2) acc[m2][j2] = (f32x4){0.f, 0.f, 0.f, 0.f};

    short8 a0[3], b0[5], a1[3], b1[5];
    LDF(a0, b0, 0);
    int ks = 0;
    for (; ks + 2 < nsteps; ks += 2) {
        LDF(a1, b1, (ks + 1) * 32);
        FMAS(a0, b0);
        LDF(a0, b0, (ks + 2) * 32);
        FMAS(a1, b1);
    }
    LDF(a1, b1, (ks + 1) * 32);
    FMAS(a0, b0);
    FMAS(a1, b1);

    size_t cb = (size_t)blockIdx.y * N * T;
    #pragma unroll
    for (int m2 = 0; m2 < 3; ++m2)
        #pragma unroll
        for (int j2 = 0; j2 < 5; ++j2)
            #pragma unroll
            for (int q = 0; q < 4; ++q) {
                int row = n0 + m2 * 16 + g * 4 + q;
                int col = t0 + j2 * 16 + r;
                Cpart[cb + (size_t)row * T + col] = acc[m2][j2][q];
            }
}

// ---------- kernel 4: epilogue ----------
__global__ void kfinal(const float* __restrict__ logits, const float* __restrict__ opts,
                       const float* __restrict__ tpts, const float* __restrict__ Cpart,
                       const float* __restrict__ ssum, const float* __restrict__ tsum4,
                       const int* __restrict__ lvl, float* __restrict__ out,
                       int N, int T, int nks) {
    int idx = blockIdx.x * 256 + threadIdx.x;
    if (idx >= N * T) return;
    int n = idx / T, t = idx - n * T;

    float lg = logits[n];
    float p = 1.f / (1.f + __expf(-lg));
    float pos = 0.25f * (1.f - p) * (1.f - p) * (-logf(p + 1e-8f));
    float neg = 0.75f * p * p * (-logf(1.f - p + 1e-8f));
    float ccls = pos - neg;

    float kp = 0.f;
    const float4* a4 = (const float4*)(opts + (size_t)n * 32);
    const float4* b4 = (const float4*)(tpts + (size_t)t * 32);
    #pragma unroll
    for (int j = 0; j < 8; ++j) {
        float4 a = a4[j], b = b4[j];
        kp += fabsf(a.x - b.x) + fabsf(a.y - b.y) + fabsf(a.z - b.z) + fabsf(a.w - b.w);
    }

    float dice = 0.f;
    if (*lvl < 2) {
        float dot = 0.f;
        for (int ks = 0; ks < nks; ++ks) dot += Cpart[(size_t)ks * N * T + idx];
        float ts = 0.f;
        #pragma unroll
        for (int ps = 0; ps < 4; ++ps) ts += tsum4[ps * T + t];
        dice = 1.f - (2.f * dot + 1.f) / (ssum[n] + ts + 1.f);
    }
    out[idx] = 2.f * ccls + 5.f * kp + 5.f * dice;
}

extern "C" void kernel_launch(void* const* d_in, const int* in_sizes, int n_in,
                              void* d_out, int out_size, void* d_ws, size_t ws_size,
                              hipStream_t stream) {
    const float* logits = (const float*)d_in[0];
    const float* cpts   = (const float*)d_in[1];
    const float* pmask  = (const float*)d_in[2];
    const float* tpts   = (const float*)d_in[3];
    const float* tmasks = (const float*)d_in[4];
    const float* coords = (const float*)d_in[5];
    const int*   lvl    = (const int*)d_in[6];
    float* out = (float*)d_out;

    int N = in_sizes[0];        // 2400
    int T = in_sizes[3] / 32;   // 160
    int P = in_sizes[5] / 2;    // 12544

    char* w = (char*)d_ws;
    auto alloc = [&](size_t bytes) {
        char* r = w;
        w += (bytes + 255) & ~(size_t)255;
        return r;
    };
    int*      idxb  = (int*)alloc((size_t)P * 4);
    uint2*    wpkb  = (uint2*)alloc((size_t)P * 8);
    ushort_t* tsamp = (ushort_t*)alloc((size_t)T * P * 2);
    ushort_t* S     = (ushort_t*)alloc((size_t)N * P * 2);
    float*    ssumb = (float*)alloc((size_t)N * 4);
    float*    tsum4 = (float*)alloc((size_t)4 * T * 4);
    size_t base_bytes = (size_t)(w - (char*)d_ws);

    int nks = 28;
    if (base_bytes + (size_t)nks * N * T * 4 > ws_size) nks = 14;
    if (base_bytes + (size_t)nks * N * T * 4 > ws_size) nks = 7;
    int nsteps = (P / 32) / nks;
    float* Cpart = (float*)alloc((size_t)nks * N * T * 4);

    kprep<<<(P + 255) / 256, 256, 0, stream>>>(coords, idxb, wpkb, P);
    ksample<0><<<dim3(T, 4), 256, 0, stream>>>(tmasks, idxb, wpkb, tsamp, tsum4, lvl, P, T);
    ksample<1><<<dim3(N, 1), 256, 0, stream>>>(pmask, idxb, wpkb, S, ssumb, lvl, P, N);
    kgemm<<<dim3(N / 96, nks), 256, 0, stream>>>(S, tsamp, Cpart, lvl, N, T, P, nsteps);
    kfinal<<<(N * T + 255) / 256, 256, 0, stream>>>(logits, cpts, tpts, Cpart, ssumb, tsum4,
                                                    lvl, out, N, T, nks);
}

// Round 5
// 131.531 us; speedup vs baseline: 1.5904x; 1.1098x over previous
//
#include <hip/hip_runtime.h>
#include <hip/hip_bf16.h>
#include <cstdint>

#define HW 128
#define MASK_ELEMS (HW * HW)
#define SBLK 512   // ksample block size: 8 waves, 64KB LDS -> 2 blocks/CU = 16 waves/CU

typedef unsigned short ushort_t;
typedef __attribute__((ext_vector_type(4))) unsigned short ushort4_t;
typedef __attribute__((ext_vector_type(8))) short short8;
typedef __attribute__((ext_vector_type(4))) float f32x4;

__device__ __forceinline__ float asf(unsigned int u) {
    union { unsigned int i; float f; } c;
    c.i = u;
    return c.f;
}
__device__ __forceinline__ ushort_t f2bf(float f) {
    union { float f; unsigned int i; } c;
    c.f = f;
    unsigned int r = c.i + 0x7FFFu + ((c.i >> 16) & 1u);  // RNE
    return (ushort_t)(r >> 16);
}

// ---------- kernel 1: per-point bilinear setup -> base idx + 4 packed bf16 weight products ----
// Base b is clamped so bx<=126, by<=126: taps {b, b+1, b+128, b+129} all in-tile.
__global__ void kprep(const float* __restrict__ coords, int* __restrict__ idx,
                      uint2* __restrict__ wpk, int P) {
    int i = blockIdx.x * 256 + threadIdx.x;
    if (i >= P) return;
    float cx = coords[2 * i], cy = coords[2 * i + 1];
    float x = cx * (float)HW - 0.5f;
    float y = cy * (float)HW - 0.5f;
    float x0f = floorf(x), y0f = floorf(y);
    float wx1 = x - x0f, wy1 = y - y0f;
    float wx0 = 1.f - wx1, wy0 = 1.f - wy1;
    int x0 = (int)x0f, y0 = (int)y0f;

    float wxA = (x0 >= 0) ? wx0 : wx1;
    float wxB = (x0 >= 0 && x0 < HW - 1) ? wx1 : 0.f;
    float wyA = (y0 >= 0) ? wy0 : wy1;
    float wyB = (y0 >= 0 && y0 < HW - 1) ? wy1 : 0.f;
    int bx = max(x0, 0), by = max(y0, 0);
    if (bx > HW - 2) { bx = HW - 2; wxB = wxA; wxA = 0.f; }
    if (by > HW - 2) { by = HW - 2; wyB = wyA; wyA = 0.f; }

    idx[i] = by * HW + bx;
    wpk[i] = make_uint2((unsigned)f2bf(wxA * wyA) | ((unsigned)f2bf(wxB * wyA) << 16),
                        (unsigned)f2bf(wxA * wyB) | ((unsigned)f2bf(wxB * wyB) << 16));
}

// One bilinear point from the packed-pair tile: 2 adjacent-base LDS words (-> ds_read2_b32).
template <int DO_SIG>
__device__ __forceinline__ float tap1(const unsigned* lmp, int b, unsigned wA, unsigned wB) {
    unsigned r0 = lmp[b];        // (m[b], m[b+1])
    unsigned r1 = lmp[b + HW];   // (m[b+128], m[b+129])
    float v = asf(wA << 16) * asf(r0 << 16) + asf(wA & 0xffff0000u) * asf(r0 & 0xffff0000u)
            + asf(wB << 16) * asf(r1 << 16) + asf(wB & 0xffff0000u) * asf(r1 & 0xffff0000u);
    if (DO_SIG) v = __builtin_amdgcn_rcpf(1.f + __expf(-v));
    return v;
}

// ---------- kernel 2: sample masks (packed-pair bf16 LDS) -> bf16 samples + row sums ----------
template <int DO_SIG>
__global__ __launch_bounds__(SBLK) void ksample(const float* __restrict__ masks,
                                                const int* __restrict__ idx,
                                                const uint2* __restrict__ wpk,
                                                ushort_t* __restrict__ samp,
                                                float* __restrict__ sum_out,
                                                const int* __restrict__ lvl, int P, int R) {
    if (*lvl >= 2) return;
    __shared__ unsigned int lmp[MASK_ELEMS];  // 64 KB: lmp[i] = (bf16 m[i], bf16 m[i+1])
    int r = blockIdx.x, tid = threadIdx.x;
    const float* m = masks + (size_t)r * MASK_ELEMS;
    #pragma unroll
    for (int j = 0; j < MASK_ELEMS / (SBLK * 4); ++j) {
        int o = j * (SBLK * 4) + tid * 4;
        float4 v = *(const float4*)&m[o];
        float nx = m[min(o + 4, MASK_ELEMS - 1)];
        unsigned e0 = (unsigned)f2bf(v.x) | ((unsigned)f2bf(v.y) << 16);
        unsigned e1 = (unsigned)f2bf(v.y) | ((unsigned)f2bf(v.z) << 16);
        unsigned e2 = (unsigned)f2bf(v.z) | ((unsigned)f2bf(v.w) << 16);
        unsigned e3 = (unsigned)f2bf(v.w) | ((unsigned)f2bf(nx) << 16);
        *(uint4*)&lmp[o] = make_uint4(e0, e1, e2, e3);
    }
    __syncthreads();

    int nq = P >> 2;                      // point-quads (P % 4 == 0)
    int qchunk = nq / gridDim.y;
    int qb = blockIdx.y * qchunk;
    int qe = (blockIdx.y == gridDim.y - 1) ? nq : qb + qchunk;
    const int4* idx4 = (const int4*)idx;
    const uint4* w4 = (const uint4*)wpk;
    ushort4_t* s4 = (ushort4_t*)(samp + (size_t)r * P);

    float sum = 0.f;
    int q = qb + tid;
    if (q < qe) {
        int4 id = idx4[q];
        uint4 wa = w4[2 * q], wb = w4[2 * q + 1];
        while (q < qe) {
            int qn = q + SBLK;
            int4 idn;
            uint4 wan, wbn;
            if (qn < qe) {                // prefetch next iteration's metadata (L2-latency hide)
                idn = idx4[qn];
                wan = w4[2 * qn];
                wbn = w4[2 * qn + 1];
            }
            float v0 = tap1<DO_SIG>(lmp, id.x, wa.x, wa.y);
            float v1 = tap1<DO_SIG>(lmp, id.y, wa.z, wa.w);
            float v2 = tap1<DO_SIG>(lmp, id.z, wb.x, wb.y);
            float v3 = tap1<DO_SIG>(lmp, id.w, wb.z, wb.w);
            ushort4_t o = {f2bf(v0), f2bf(v1), f2bf(v2), f2bf(v3)};
            s4[q] = o;
            sum += (v0 + v1) + (v2 + v3);
            q = qn;
            id = idn; wa = wan; wb = wbn;
        }
    }

    __syncthreads();
    float* red = (float*)lmp;
    red[tid] = sum;
    __syncthreads();
    for (int s2 = SBLK / 2; s2 > 0; s2 >>= 1) {
        if (tid < s2) red[tid] += red[tid + s2];
        __syncthreads();
    }
    if (tid == 0) sum_out[blockIdx.y * R + r] = red[0];
}

// ---------- kernel 3: MFMA split-K GEMM: Cpart[ks][n][t] = sum_k S[n,k]*Tm[t,k] ----------
#define LDF(Aarr, Barr, kof)                                                              \
    do {                                                                                  \
        _Pragma("unroll") for (int m_ = 0; m_ < 3; ++m_)                                  \
            Aarr[m_] = *(const short8*)(pa + (size_t)m_ * 16 * P + (kof));                \
        _Pragma("unroll") for (int j_ = 0; j_ < 5; ++j_)                                  \
            Barr[j_] = *(const short8*)(pb + (size_t)j_ * 16 * P + (kof));                \
    } while (0)

#define FMAS(Aarr, Barr)                                                                  \
    do {                                                                                  \
        _Pragma("unroll") for (int m_ = 0; m_ < 3; ++m_) {                                \
            _Pragma("unroll") for (int j_ = 0; j_ < 5; ++j_)                              \
                acc[m_][j_] = __builtin_amdgcn_mfma_f32_16x16x32_bf16(                    \
                    Aarr[m_], Barr[j_], acc[m_][j_], 0, 0, 0);                            \
        }                                                                                 \
    } while (0)

__global__ __launch_bounds__(256) void kgemm(const ushort_t* __restrict__ S,
                                             const ushort_t* __restrict__ Tm,
                                             float* __restrict__ Cpart,
                                             const int* __restrict__ lvl,
                                             int N, int T, int P, int nsteps) {
    if (*lvl >= 2) return;
    int tid = threadIdx.x;
    int wid = tid >> 6, lane = tid & 63;
    int wm = wid >> 1, wt = wid & 1;
    int r = lane & 15, g = lane >> 4;
    int n0 = blockIdx.x * 96 + wm * 48;
    int t0 = wt * 80;
    size_t k0 = (size_t)blockIdx.y * nsteps * 32 + g * 8;
    const ushort_t* pa = S + (size_t)(n0 + r) * P + k0;
    const ushort_t* pb = Tm + (size_t)(t0 + r) * P + k0;

    f32x4 acc[3][5];
    #pragma unroll
    for (int m2 = 0; m2 < 3; ++m2)
        #pragma unroll
        for (int j2 = 0; j2 < 5; ++j2) acc[m2][j2] = (f32x4){0.f, 0.f, 0.f, 0.f};

    short8 a0[3], b0[5], a1[3], b1[5];
    LDF(a0, b0, 0);
    int ks = 0;
    for (; ks + 2 < nsteps; ks += 2) {
        LDF(a1, b1, (ks + 1) * 32);
        FMAS(a0, b0);
        LDF(a0, b0, (ks + 2) * 32);
        FMAS(a1, b1);
    }
    LDF(a1, b1, (ks + 1) * 32);
    FMAS(a0, b0);
    FMAS(a1, b1);

    size_t cb = (size_t)blockIdx.y * N * T;
    #pragma unroll
    for (int m2 = 0; m2 < 3; ++m2)
        #pragma unroll
        for (int j2 = 0; j2 < 5; ++j2)
            #pragma unroll
            for (int q = 0; q < 4; ++q) {
                int row = n0 + m2 * 16 + g * 4 + q;
                int col = t0 + j2 * 16 + r;
                Cpart[cb + (size_t)row * T + col] = acc[m2][j2][q];
            }
}

// ---------- kernel 4: epilogue ----------
__global__ void kfinal(const float* __restrict__ logits, const float* __restrict__ opts,
                       const float* __restrict__ tpts, const float* __restrict__ Cpart,
                       const float* __restrict__ ssum, const float* __restrict__ tsum4,
                       const int* __restrict__ lvl, float* __restrict__ out,
                       int N, int T, int nks) {
    int idx = blockIdx.x * 256 + threadIdx.x;
    if (idx >= N * T) return;
    int n = idx / T, t = idx - n * T;

    float lg = logits[n];
    float p = 1.f / (1.f + __expf(-lg));
    float pos = 0.25f * (1.f - p) * (1.f - p) * (-logf(p + 1e-8f));
    float neg = 0.75f * p * p * (-logf(1.f - p + 1e-8f));
    float ccls = pos - neg;

    float kp = 0.f;
    const float4* a4 = (const float4*)(opts + (size_t)n * 32);
    const float4* b4 = (const float4*)(tpts + (size_t)t * 32);
    #pragma unroll
    for (int j = 0; j < 8; ++j) {
        float4 a = a4[j], b = b4[j];
        kp += fabsf(a.x - b.x) + fabsf(a.y - b.y) + fabsf(a.z - b.z) + fabsf(a.w - b.w);
    }

    float dice = 0.f;
    if (*lvl < 2) {
        float dot = 0.f;
        for (int ks = 0; ks < nks; ++ks) dot += Cpart[(size_t)ks * N * T + idx];
        float ts = 0.f;
        #pragma unroll
        for (int ps = 0; ps < 4; ++ps) ts += tsum4[ps * T + t];
        dice = 1.f - (2.f * dot + 1.f) / (ssum[n] + ts + 1.f);
    }
    out[idx] = 2.f * ccls + 5.f * kp + 5.f * dice;
}

extern "C" void kernel_launch(void* const* d_in, const int* in_sizes, int n_in,
                              void* d_out, int out_size, void* d_ws, size_t ws_size,
                              hipStream_t stream) {
    const float* logits = (const float*)d_in[0];
    const float* cpts   = (const float*)d_in[1];
    const float* pmask  = (const float*)d_in[2];
    const float* tpts   = (const float*)d_in[3];
    const float* tmasks = (const float*)d_in[4];
    const float* coords = (const float*)d_in[5];
    const int*   lvl    = (const int*)d_in[6];
    float* out = (float*)d_out;

    int N = in_sizes[0];        // 2400
    int T = in_sizes[3] / 32;   // 160
    int P = in_sizes[5] / 2;    // 12544

    char* w = (char*)d_ws;
    auto alloc = [&](size_t bytes) {
        char* r = w;
        w += (bytes + 255) & ~(size_t)255;
        return r;
    };
    int*      idxb  = (int*)alloc((size_t)P * 4);
    uint2*    wpkb  = (uint2*)alloc((size_t)P * 8);
    ushort_t* tsamp = (ushort_t*)alloc((size_t)T * P * 2);
    ushort_t* S     = (ushort_t*)alloc((size_t)N * P * 2);
    float*    ssumb = (float*)alloc((size_t)N * 4);
    float*    tsum4 = (float*)alloc((size_t)4 * T * 4);
    size_t base_bytes = (size_t)(w - (char*)d_ws);

    int nks = 28;
    if (base_bytes + (size_t)nks * N * T * 4 > ws_size) nks = 14;
    if (base_bytes + (size_t)nks * N * T * 4 > ws_size) nks = 7;
    int nsteps = (P / 32) / nks;
    float* Cpart = (float*)alloc((size_t)nks * N * T * 4);

    kprep<<<(P + 255) / 256, 256, 0, stream>>>(coords, idxb, wpkb, P);
    ksample<0><<<dim3(T, 4), SBLK, 0, stream>>>(tmasks, idxb, wpkb, tsamp, tsum4, lvl, P, T);
    ksample<1><<<dim3(N, 1), SBLK, 0, stream>>>(pmask, idxb, wpkb, S, ssumb, lvl, P, N);
    kgemm<<<dim3(N / 96, nks), 256, 0, stream>>>(S, tsamp, Cpart, lvl, N, T, P, nsteps);
    kfinal<<<(N * T + 255) / 256, 256, 0, stream>>>(logits, cpts, tpts, Cpart, ssumb, tsum4,
                                                    lvl, out, N, T, nks);
}

// Round 6
// 120.104 us; speedup vs baseline: 1.7417x; 1.0951x over previous
//
#include <hip/hip_runtime.h>
#include <hip/hip_bf16.h>
#include <cstdint>

#define HW 128
#define MASK_ELEMS (HW * HW)
#define SBLK 1024      // sampler block size (16 waves)
#define NBLK 256       // sampler grid size (1 block/CU, 128KB LDS)

typedef unsigned short ushort_t;
typedef __attribute__((ext_vector_type(4))) unsigned short ushort4_t;
typedef __attribute__((ext_vector_type(8))) short short8;
typedef __attribute__((ext_vector_type(4))) float f32x4;

__device__ __forceinline__ float asf(unsigned int u) {
    union { unsigned int i; float f; } c;
    c.i = u;
    return c.f;
}
__device__ __forceinline__ ushort_t f2bf(float f) {
    union { float f; unsigned int i; } c;
    c.f = f;
    unsigned int r = c.i + 0x7FFFu + ((c.i >> 16) & 1u);  // RNE
    return (ushort_t)(r >> 16);
}

// ---------- kernel 1: per-point bilinear setup -> base idx + 4 packed bf16 weight products ----
// Base b clamped so bx<=126, by<=126: taps {b, b+1, b+128, b+129} all in [0,16384).
__global__ void kprep(const float* __restrict__ coords, int* __restrict__ idx,
                      uint2* __restrict__ wpk, int P) {
    int i = blockIdx.x * 256 + threadIdx.x;
    if (i >= P) return;
    float cx = coords[2 * i], cy = coords[2 * i + 1];
    float x = cx * (float)HW - 0.5f;
    float y = cy * (float)HW - 0.5f;
    float x0f = floorf(x), y0f = floorf(y);
    float wx1 = x - x0f, wy1 = y - y0f;
    float wx0 = 1.f - wx1, wy0 = 1.f - wy1;
    int x0 = (int)x0f, y0 = (int)y0f;

    float wxA = (x0 >= 0) ? wx0 : wx1;
    float wxB = (x0 >= 0 && x0 < HW - 1) ? wx1 : 0.f;
    float wyA = (y0 >= 0) ? wy0 : wy1;
    float wyB = (y0 >= 0 && y0 < HW - 1) ? wy1 : 0.f;
    int bx = max(x0, 0), by = max(y0, 0);
    if (bx > HW - 2) { bx = HW - 2; wxB = wxA; wxA = 0.f; }
    if (by > HW - 2) { by = HW - 2; wyB = wyA; wyA = 0.f; }

    idx[i] = by * HW + bx;
    wpk[i] = make_uint2((unsigned)f2bf(wxA * wyA) | ((unsigned)f2bf(wxB * wyA) << 16),
                        (unsigned)f2bf(wxA * wyB) | ((unsigned)f2bf(wxB * wyB) << 16));
}

// ---------- kernel 2: persistent fused sampler (pred + tgt masks) ----------
// 128KB LDS double-buffer; async global_load_lds stages mask i+1 while sampling mask i.
// Point metadata preloaded into registers ONCE (mask-invariant) so the sample loop has no
// vmem -> in-order vmcnt never waits on the in-flight stage stream.
__device__ __forceinline__ void stage_mask(const float* __restrict__ g, float* l, int tid) {
    #pragma unroll
    for (int j = 0; j < MASK_ELEMS / (SBLK * 4); ++j) {   // 4 x 16B per thread
        int o = j * SBLK * 4 + tid * 4;
        __builtin_amdgcn_global_load_lds(
            (const __attribute__((address_space(1))) unsigned int*)(const void*)(g + o),
            (__attribute__((address_space(3))) unsigned int*)(void*)(l + o), 16, 0, 0);
    }
}

__global__ __launch_bounds__(SBLK, 4) void ksamp_all(
        const float* __restrict__ pmask, const float* __restrict__ tmasks,
        const int* __restrict__ idx, const uint2* __restrict__ wpk,
        ushort_t* __restrict__ S, ushort_t* __restrict__ tsamp,
        float* __restrict__ ssum, float* __restrict__ tsum,
        const int* __restrict__ lvl, int N, int T, int P) {
    if (*lvl >= 2) return;
    __shared__ float buf[2][MASK_ELEMS];     // 128 KB
    __shared__ float wred[2][SBLK / 64];
    int tid = threadIdx.x;
    int NM = N + T;
    int nq = P >> 2;                          // point-quads

    // ---- preload mask-invariant point metadata into registers ----
    int4 idr[4];
    uint4 war[4], wbr[4];
    #pragma unroll
    for (int it = 0; it < 4; ++it) {
        int q = it * SBLK + tid;
        if (q < nq) {
            idr[it] = ((const int4*)idx)[q];
            war[it] = ((const uint4*)wpk)[2 * q];
            wbr[it] = ((const uint4*)wpk)[2 * q + 1];
        } else {
            idr[it] = make_int4(0, 0, 0, 0);
            war[it] = make_uint4(0, 0, 0, 0);
            wbr[it] = make_uint4(0, 0, 0, 0);
        }
    }

    int b = blockIdx.x;
    if (b < NM) {
        const float* m0 = (b < N) ? pmask + (size_t)b * MASK_ELEMS
                                  : tmasks + (size_t)(b - N) * MASK_ELEMS;
        stage_mask(m0, buf[0], tid);
    }
    asm volatile("s_waitcnt vmcnt(0)" ::: "memory");
    __syncthreads();

    int cur = 0, cnt = 0;
    for (int mi = b; mi < NM; mi += NBLK, ++cnt) {
        int nxt = mi + NBLK;
        if (nxt < NM) {                        // issue next mask's stage (async, overlaps below)
            const float* mn = (nxt < N) ? pmask + (size_t)nxt * MASK_ELEMS
                                        : tmasks + (size_t)(nxt - N) * MASK_ELEMS;
            stage_mask(mn, buf[cur ^ 1], tid);
        }
        const float* lm = buf[cur];
        bool sig = (mi < N);
        ushort4_t* o4 = sig ? (ushort4_t*)(S + (size_t)mi * P)
                            : (ushort4_t*)(tsamp + (size_t)(mi - N) * P);
        float sum = 0.f;
        #pragma unroll
        for (int it = 0; it < 4; ++it) {
            int q = it * SBLK + tid;
            if (q < nq) {
                float v[4];
                int bi[4] = {idr[it].x, idr[it].y, idr[it].z, idr[it].w};
                unsigned wa[4] = {war[it].x, war[it].z, wbr[it].x, wbr[it].z};
                unsigned wb[4] = {war[it].y, war[it].w, wbr[it].y, wbr[it].w};
                #pragma unroll
                for (int p2 = 0; p2 < 4; ++p2) {
                    int bb = bi[p2];
                    float t00 = lm[bb], t01 = lm[bb + 1];
                    float t10 = lm[bb + HW], t11 = lm[bb + HW + 1];
                    float vv = asf(wa[p2] << 16) * t00 + asf(wa[p2] & 0xffff0000u) * t01
                             + asf(wb[p2] << 16) * t10 + asf(wb[p2] & 0xffff0000u) * t11;
                    if (sig) vv = __builtin_amdgcn_rcpf(1.f + __expf(-vv));
                    v[p2] = vv;
                }
                ushort4_t o = {f2bf(v[0]), f2bf(v[1]), f2bf(v[2]), f2bf(v[3])};
                o4[q] = o;
                sum += (v[0] + v[1]) + (v[2] + v[3]);
            }
        }
        #pragma unroll
        for (int m2 = 32; m2 > 0; m2 >>= 1) sum += __shfl_xor(sum, m2, 64);
        if ((tid & 63) == 0) wred[cnt & 1][tid >> 6] = sum;
        asm volatile("s_waitcnt vmcnt(0)" ::: "memory");  // next-mask stage landed
        __syncthreads();                                   // + wred visible, buf[cur] free
        if (tid == 0) {
            float s = 0.f;
            #pragma unroll
            for (int w2 = 0; w2 < SBLK / 64; ++w2) s += wred[cnt & 1][w2];
            if (sig) ssum[mi] = s;
            else tsum[mi - N] = s;
        }
        cur ^= 1;
    }
}

// ---------- kernel 3: MFMA split-K GEMM: Cpart[ks][n][t] = sum_k S[n,k]*Tm[t,k] ----------
#define LDF(Aarr, Barr, kof)                                                              \
    do {                                                                                  \
        _Pragma("unroll") for (int m_ = 0; m_ < 3; ++m_)                                  \
            Aarr[m_] = *(const short8*)(pa + (size_t)m_ * 16 * P + (kof));                \
        _Pragma("unroll") for (int j_ = 0; j_ < 5; ++j_)                                  \
            Barr[j_] = *(const short8*)(pb + (size_t)j_ * 16 * P + (kof));                \
    } while (0)

#define FMAS(Aarr, Barr)                                                                  \
    do {                                                                                  \
        _Pragma("unroll") for (int m_ = 0; m_ < 3; ++m_) {                                \
            _Pragma("unroll") for (int j_ = 0; j_ < 5; ++j_)                              \
                acc[m_][j_] = __builtin_amdgcn_mfma_f32_16x16x32_bf16(                    \
                    Aarr[m_], Barr[j_], acc[m_][j_], 0, 0, 0);                            \
        }                                                                                 \
    } while (0)

__global__ __launch_bounds__(256) void kgemm(const ushort_t* __restrict__ S,
                                             const ushort_t* __restrict__ Tm,
                                             float* __restrict__ Cpart,
                                             const int* __restrict__ lvl,
                                             int N, int T, int P, int nsteps) {
    if (*lvl >= 2) return;
    int tid = threadIdx.x;
    int wid = tid >> 6, lane = tid & 63;
    int wm = wid >> 1, wt = wid & 1;
    int r = lane & 15, g = lane >> 4;
    int n0 = blockIdx.x * 96 + wm * 48;
    int t0 = wt * 80;
    size_t k0 = (size_t)blockIdx.y * nsteps * 32 + g * 8;
    const ushort_t* pa = S + (size_t)(n0 + r) * P + k0;
    const ushort_t* pb = Tm + (size_t)(t0 + r) * P + k0;

    f32x4 acc[3][5];
    #pragma unroll
    for (int m2 = 0; m2 < 3; ++m2)
        #pragma unroll
        for (int j2 = 0; j2 < 5; ++j2) acc[m2][j2] = (f32x4){0.f, 0.f, 0.f, 0.f};

    short8 a0[3], b0[5], a1[3], b1[5];
    LDF(a0, b0, 0);
    int ks = 0;
    for (; ks + 2 < nsteps; ks += 2) {
        LDF(a1, b1, (ks + 1) * 32);
        FMAS(a0, b0);
        LDF(a0, b0, (ks + 2) * 32);
        FMAS(a1, b1);
    }
    LDF(a1, b1, (ks + 1) * 32);
    FMAS(a0, b0);
    FMAS(a1, b1);

    size_t cb = (size_t)blockIdx.y * N * T;
    #pragma unroll
    for (int m2 = 0; m2 < 3; ++m2)
        #pragma unroll
        for (int j2 = 0; j2 < 5; ++j2)
            #pragma unroll
            for (int q = 0; q < 4; ++q) {
                int row = n0 + m2 * 16 + g * 4 + q;
                int col = t0 + j2 * 16 + r;
                Cpart[cb + (size_t)row * T + col] = acc[m2][j2][q];
            }
}

// ---------- kernel 4: epilogue ----------
__global__ void kfinal(const float* __restrict__ logits, const float* __restrict__ opts,
                       const float* __restrict__ tpts, const float* __restrict__ Cpart,
                       const float* __restrict__ ssum, const float* __restrict__ tsum,
                       const int* __restrict__ lvl, float* __restrict__ out,
                       int N, int T, int nks) {
    int idx = blockIdx.x * 256 + threadIdx.x;
    if (idx >= N * T) return;
    int n = idx / T, t = idx - n * T;

    float lg = logits[n];
    float p = 1.f / (1.f + __expf(-lg));
    float pos = 0.25f * (1.f - p) * (1.f - p) * (-logf(p + 1e-8f));
    float neg = 0.75f * p * p * (-logf(1.f - p + 1e-8f));
    float ccls = pos - neg;

    float kp = 0.f;
    const float4* a4 = (const float4*)(opts + (size_t)n * 32);
    const float4* b4 = (const float4*)(tpts + (size_t)t * 32);
    #pragma unroll
    for (int j = 0; j < 8; ++j) {
        float4 a = a4[j], b = b4[j];
        kp += fabsf(a.x - b.x) + fabsf(a.y - b.y) + fabsf(a.z - b.z) + fabsf(a.w - b.w);
    }

    float dice = 0.f;
    if (*lvl < 2) {
        float dot = 0.f;
        for (int ks = 0; ks < nks; ++ks) dot += Cpart[(size_t)ks * N * T + idx];
        dice = 1.f - (2.f * dot + 1.f) / (ssum[n] + tsum[t] + 1.f);
    }
    out[idx] = 2.f * ccls + 5.f * kp + 5.f * dice;
}

extern "C" void kernel_launch(void* const* d_in, const int* in_sizes, int n_in,
                              void* d_out, int out_size, void* d_ws, size_t ws_size,
                              hipStream_t stream) {
    const float* logits = (const float*)d_in[0];
    const float* cpts   = (const float*)d_in[1];
    const float* pmask  = (const float*)d_in[2];
    const float* tpts   = (const float*)d_in[3];
    const float* tmasks = (const float*)d_in[4];
    const float* coords = (const float*)d_in[5];
    const int*   lvl    = (const int*)d_in[6];
    float* out = (float*)d_out;

    int N = in_sizes[0];        // 2400
    int T = in_sizes[3] / 32;   // 160
    int P = in_sizes[5] / 2;    // 12544

    char* w = (char*)d_ws;
    auto alloc = [&](size_t bytes) {
        char* r = w;
        w += (bytes + 255) & ~(size_t)255;
        return r;
    };
    int*      idxb  = (int*)alloc((size_t)P * 4);
    uint2*    wpkb  = (uint2*)alloc((size_t)P * 8);
    ushort_t* tsamp = (ushort_t*)alloc((size_t)T * P * 2);
    ushort_t* S     = (ushort_t*)alloc((size_t)N * P * 2);
    float*    ssumb = (float*)alloc((size_t)N * 4);
    float*    tsumb = (float*)alloc((size_t)T * 4);
    size_t base_bytes = (size_t)(w - (char*)d_ws);

    int nks = 28;
    if (base_bytes + (size_t)nks * N * T * 4 > ws_size) nks = 14;
    if (base_bytes + (size_t)nks * N * T * 4 > ws_size) nks = 7;
    int nsteps = (P / 32) / nks;
    float* Cpart = (float*)alloc((size_t)nks * N * T * 4);

    kprep<<<(P + 255) / 256, 256, 0, stream>>>(coords, idxb, wpkb, P);
    ksamp_all<<<NBLK, SBLK, 0, stream>>>(pmask, tmasks, idxb, wpkb, S, tsamp,
                                         ssumb, tsumb, lvl, N, T, P);
    kgemm<<<dim3(N / 96, nks), 256, 0, stream>>>(S, tsamp, Cpart, lvl, N, T, P, nsteps);
    kfinal<<<(N * T + 255) / 256, 256, 0, stream>>>(logits, cpts, tpts, Cpart, ssumb, tsumb,
                                                    lvl, out, N, T, nks);
}